// Round 4
// baseline (789.586 us; speedup 1.0000x reference)
//
#include <hip/hip_runtime.h>

typedef unsigned int u32;
typedef unsigned short u16;
typedef float f32x4 __attribute__((ext_vector_type(4)));
typedef float f32x16 __attribute__((ext_vector_type(16)));
typedef u16 us4 __attribute__((ext_vector_type(4)));
typedef u16 us8 __attribute__((ext_vector_type(8)));
typedef __bf16 bf16x8 __attribute__((ext_vector_type(8)));

__device__ __forceinline__ u16 f2bf(float f) {
  u32 u = __builtin_bit_cast(u32, f);
  u += 0x7fffu + ((u >> 16) & 1u);
  return (u16)(u >> 16);
}
__device__ __forceinline__ float bf2f(u16 h) {
  u32 u = ((u32)h) << 16;
  return __builtin_bit_cast(float, u);
}
__device__ __forceinline__ void async16(const void* g, void* l) {
  __builtin_amdgcn_global_load_lds((const __attribute__((address_space(1))) void*)g,
                                   (__attribute__((address_space(3))) void*)l, 16, 0, 0);
}

// ---------------------------------------------------------------------------
// gemm256: 256x256 tile, BK=64, 8 waves (2M x 4N), 8-phase schedule with
// counted vmcnt (T3+T4), XOR-4 LDS swizzle (T2, 0 conflicts measured R2/R3),
// setprio (T5), XCD col-partitioned block mapping (T1; R3: FETCH 270->98MB).
// C = A * B^T.  Phase = (set, ks, mh): one M-half quadrant x one K-half:
// 4 A ds_reads (+4 B ds_reads on mh=0, held in regs for mh=1), 16 MFMA.
//
// R3 post-mortem: hand-inserted "lgkmcnt(0) + sched_barrier(0)" per phase
// forced ALL ds_reads to return before ANY MFMA and fenced the scheduler;
// rule #18 needs that only for inline-asm ds_reads.  Ours are IR loads ->
// compiler emits fine-grained lgkmcnt so MFMA0 starts when frag0 lands.
// Removed both (R4).  Ordering safety: reads/writes can't cross the asm
// s_barrier ("memory" clobber); MFMA ordered by dataflow; staging-vs-read
// ordering is vmcnt(own wave) + closing barrier, wave-symmetric.
//
// Staging windows (every piece staged strictly after its last LDS read,
// forced complete >=1 phase before its first read):
//   p0: stage As1.K1(t1)   p1: Bs1.K1(t1)  vm8(no-op)   (read p6/p7)
//   p2: stage As0.K0(t2)   p3: Bs0.K0(t2)  vm8          (read next p0/p1)
//   p4: stage As0.K1(t2)   p5: Bs0.K1(t2)  vm8          (read next p2/p3)
//   p6: stage As1.K0(t3)   p7: Bs1.K0(t3)  vm8          (read next p4/p5)
// Last iter: p0/p1 stage only; waits peel vm8 / vm4 / vm0.
// ---------------------------------------------------------------------------
#define STG(GP, LP, OFF, KOFF)                              \
  {                                                         \
    async16((GP) + (KOFF), (LP) + (OFF));                   \
    async16((GP) + 128L * K + (KOFF), (LP) + (OFF) + 4096); \
  }

#define PHASE(SET, KS, MH, STAGE_STMT, TAIL_STMT)                               \
  {                                                                             \
    const u16* Ap_ = As + (SET) * 16384 + (KS) * 8192;                          \
    const u16* Bp_ = Bs + (SET) * 16384 + (KS) * 8192;                          \
    us8 af0 = *(const us8*)(Ap_ + ra[(MH) * 4 + 0]);                            \
    us8 af1 = *(const us8*)(Ap_ + ra[(MH) * 4 + 1]);                            \
    us8 af2 = *(const us8*)(Ap_ + ra[(MH) * 4 + 2]);                            \
    us8 af3 = *(const us8*)(Ap_ + ra[(MH) * 4 + 3]);                            \
    if ((MH) == 0) {                                                            \
      _Pragma("unroll") for (int nf = 0; nf < 4; ++nf)                          \
          bfr[nf] = *(const us8*)(Bp_ + rb[nf]);                                \
    }                                                                           \
    STAGE_STMT;                                                                 \
    asm volatile("s_barrier" ::: "memory");                                     \
    __builtin_amdgcn_s_setprio(1);                                              \
    _Pragma("unroll") for (int nf = 0; nf < 4; ++nf) {                          \
      acc[(MH) * 4 + 0][nf] = __builtin_amdgcn_mfma_f32_16x16x32_bf16(          \
          __builtin_bit_cast(bf16x8, af0), __builtin_bit_cast(bf16x8, bfr[nf]), \
          acc[(MH) * 4 + 0][nf], 0, 0, 0);                                      \
      acc[(MH) * 4 + 1][nf] = __builtin_amdgcn_mfma_f32_16x16x32_bf16(          \
          __builtin_bit_cast(bf16x8, af1), __builtin_bit_cast(bf16x8, bfr[nf]), \
          acc[(MH) * 4 + 1][nf], 0, 0, 0);                                      \
      acc[(MH) * 4 + 2][nf] = __builtin_amdgcn_mfma_f32_16x16x32_bf16(          \
          __builtin_bit_cast(bf16x8, af2), __builtin_bit_cast(bf16x8, bfr[nf]), \
          acc[(MH) * 4 + 2][nf], 0, 0, 0);                                      \
      acc[(MH) * 4 + 3][nf] = __builtin_amdgcn_mfma_f32_16x16x32_bf16(          \
          __builtin_bit_cast(bf16x8, af3), __builtin_bit_cast(bf16x8, bfr[nf]), \
          acc[(MH) * 4 + 3][nf], 0, 0, 0);                                      \
    }                                                                           \
    __builtin_amdgcn_s_setprio(0);                                              \
    TAIL_STMT;                                                                  \
    asm volatile("s_barrier" ::: "memory");                                     \
  }

__global__ __launch_bounds__(512, 2) void gemm256(const u16* __restrict__ A,
                                                  const u16* __restrict__ B,
                                                  u16* __restrict__ U,
                                                  u16* __restrict__ G, int K) {
  __shared__ __align__(16) u16 As[32768];  // 2 sets x 2 K-halves x 256x32
  __shared__ __align__(16) u16 Bs[32768];
  const int tid = threadIdx.x;
  const int lane = tid & 63;
  const int wave = tid >> 6;
  const int wm = wave >> 2;  // 0..1 : 128-row block
  const int wn = wave & 3;   // 0..3 : 64-col block
  const int l15 = lane & 15;
  const int kc2 = lane >> 4;                // chunk within K-half
  const int pc2s = kc2 ^ ((l15 >> 1) & 3);  // XOR-4 swizzle (read side)

  // XCD-aware mapping from true dispatch order (x fastest).
  const int nbx = (int)gridDim.x;  // col tiles (32)
  const int d = (int)blockIdx.y * nbx + (int)blockIdx.x;
  const int cpn = nbx >> 3;        // cols per XCD (4)
  const int xcd = d & 7;
  const int s = d >> 3;
  const long colBase = (long)(xcd * cpn + (s % cpn)) << 8;
  const long rowBase = (long)(s / cpn) << 8;

  // staging: thread covers tile row (tid>>2)(+128), swizzled chunk of 8.
  const int c0 = ((tid & 3) ^ ((tid >> 3) & 3)) << 3;
  const u16* Ag = A + (rowBase + (tid >> 2)) * (long)K + c0;
  const u16* Bg = B + (colBase + (tid >> 2)) * (long)K + c0;
  u16* Alds = As + tid * 8;
  u16* Blds = Bs + tid * 8;

  int ra[8], rb[4];
#pragma unroll
  for (int mf = 0; mf < 8; ++mf)
    ra[mf] = (wm * 128 + mf * 16 + l15) * 32 + pc2s * 8;
#pragma unroll
  for (int nf = 0; nf < 4; ++nf)
    rb[nf] = (wn * 64 + nf * 16 + l15) * 32 + pc2s * 8;

  f32x4 acc[8][4] = {};
  us8 bfr[4];

  // prologue: tile0 (both K-halves) + tile1.K0
  STG(Ag, Alds, 0, 0);
  STG(Bg, Blds, 0, 0);
  STG(Ag, Alds, 8192, 32);
  STG(Bg, Blds, 8192, 32);
  STG(Ag, Alds, 16384, 64);
  STG(Bg, Blds, 16384, 64);
  asm volatile("s_waitcnt vmcnt(4)" ::: "memory");
  asm volatile("s_barrier" ::: "memory");

  const int nIter = K >> 7;
  for (int t = 0; t < nIter; ++t) {
    const int k1 = (2 * t + 1) * 64;
    const int k2 = (2 * t + 2) * 64;
    const int k3 = (2 * t + 3) * 64;
    const bool full = (t < nIter - 1);
    PHASE(0, 0, 0, { STG(Ag, Alds, 24576, k1 + 32); }, {});
    PHASE(0, 0, 1, { STG(Bg, Blds, 24576, k1 + 32); },
          { asm volatile("s_waitcnt vmcnt(8)" ::: "memory"); });
    PHASE(0, 1, 0, { if (full) STG(Ag, Alds, 0, k2); }, {});
    PHASE(0, 1, 1, { if (full) STG(Bg, Blds, 0, k2); },
          {
            if (full) asm volatile("s_waitcnt vmcnt(8)" ::: "memory");
            else asm volatile("s_waitcnt vmcnt(4)" ::: "memory");
          });
    PHASE(1, 0, 0, { if (full) STG(Ag, Alds, 8192, k2 + 32); }, {});
    PHASE(1, 0, 1, { if (full) STG(Bg, Blds, 8192, k2 + 32); },
          {
            if (full) asm volatile("s_waitcnt vmcnt(8)" ::: "memory");
            else asm volatile("s_waitcnt vmcnt(0)" ::: "memory");
          });
    PHASE(1, 1, 0, { if (full) STG(Ag, Alds, 16384, k3); }, {});
    PHASE(1, 1, 1, { if (full) STG(Bg, Blds, 16384, k3); },
          { if (full) asm volatile("s_waitcnt vmcnt(8)" ::: "memory"); });
  }

  // epilogue: C/D 16x16 layout col=lane&15, row=(lane>>4)*4+reg  [m89]
  const int gate = (colBase >= 4096);
  u16* Out = gate ? G : U;
  const long cb = gate ? (colBase - 4096) : colBase;
#pragma unroll
  for (int mf = 0; mf < 8; ++mf) {
    long row0 = rowBase + wm * 128 + mf * 16 + (lane >> 4) * 4;
#pragma unroll
    for (int nf = 0; nf < 4; ++nf) {
      long col = cb + wn * 64 + nf * 16 + l15;
#pragma unroll
      for (int r = 0; r < 4; ++r) {
        float v = acc[mf][nf][r];
        if (gate) v = v / (1.f + __expf(-v));
        Out[(row0 + r) * 4096 + col] = f2bf(v);
      }
    }
  }
}

// ---------------------------------------------------------------------------
// C = A * B^T.  A: M x K bf16 row-major. B: N x K bf16 row-major.
// BK=64, XOR-8 swizzled LDS (conflict-free, verified r7), 32x32x16 MFMA.
// A/B frag: [m|n = lane&31][k = 8*(lane>>5) + j]; C/D: col=lane&31,
// row=(reg&3)+8*(reg>>2)+4*(lane>>5)  [m74/m101].
// ACT: 0 fp32, 3 fp32 softplus(+bias), 4 bf16 softplus(+bias).
// SPLITK: blockIdx.z K-slice, C offset per z.
// ---------------------------------------------------------------------------
template <int ACT, bool SPLITK = false>
__global__ __launch_bounds__(256) void gemm_bt(const u16* __restrict__ A,
                                               const u16* __restrict__ B,
                                               void* __restrict__ Cv,
                                               const float* __restrict__ bias,
                                               int K, int ldc) {
  __shared__ __align__(16) u16 As[128 * 64];
  __shared__ __align__(16) u16 Bs[128 * 64];
  const int tid = threadIdx.x;
  const int lane = tid & 63;
  const int wave = tid >> 6;
  const int ln = lane & 31;   // m/n within 32-tile
  const int hw = lane >> 5;   // half-wave k selector
  const int wm = (wave >> 1) << 6;
  const int wn = (wave & 1) << 6;
  const long rowBase = (long)blockIdx.y << 7;
  const long colBase = (long)blockIdx.x << 7;

  int kStart = 0, kEnd = K;
  if constexpr (SPLITK) {
    int kn = K / gridDim.z;
    kStart = blockIdx.z * kn;
    kEnd = kStart + kn;
  }

  const int rr = tid >> 3;
  const int qg = (tid & 7) ^ (rr & 7);
  const u16* Ag = A + (rowBase + rr) * (long)K + qg * 8;
  const u16* Bg = B + (colBase + rr) * (long)K + qg * 8;
  u16* Al = As + tid * 8;
  u16* Bl = Bs + tid * 8;

  f32x16 acc[2][2] = {};
  const int l7 = ln & 7;

  for (int k0 = kStart; k0 < kEnd; k0 += 64) {
#pragma unroll
    for (int c = 0; c < 4; ++c) {
      async16(Ag + 32L * c * K + k0, Al + 2048 * c);
      async16(Bg + 32L * c * K + k0, Bl + 2048 * c);
    }
    __syncthreads();
#pragma unroll
    for (int s = 0; s < 4; ++s) {  // K=16 slice; chunk pair {2s, 2s+1}
      const int xa = ((s * 2 + hw) ^ l7) * 8;
      us8 af[2], bfr[2];
#pragma unroll
      for (int i = 0; i < 2; ++i)
        af[i] = *(const us8*)(As + (wm + i * 32 + ln) * 64 + xa);
#pragma unroll
      for (int i = 0; i < 2; ++i)
        bfr[i] = *(const us8*)(Bs + (wn + i * 32 + ln) * 64 + xa);
#pragma unroll
      for (int i = 0; i < 2; ++i)
#pragma unroll
        for (int j = 0; j < 2; ++j)
          acc[i][j] = __builtin_amdgcn_mfma_f32_32x32x16_bf16(
              __builtin_bit_cast(bf16x8, af[i]), __builtin_bit_cast(bf16x8, bfr[j]),
              acc[i][j], 0, 0, 0);
    }
    __syncthreads();
  }

  float* Cf = (float*)Cv;
  if constexpr (SPLITK)
    Cf += (size_t)blockIdx.z * ((size_t)gridDim.y * 128 * ldc);

#pragma unroll
  for (int i = 0; i < 2; ++i)
#pragma unroll
    for (int j = 0; j < 2; ++j)
#pragma unroll
      for (int r = 0; r < 16; ++r) {
        long row = rowBase + wm + i * 32 + (r & 3) + 8 * (r >> 2) + 4 * hw;
        long col = colBase + wn + j * 32 + ln;
        float v = acc[i][j][r];
        if constexpr (ACT == 0) {
          Cf[row * ldc + col] = v;
        } else if constexpr (ACT == 3) {
          v += bias[col];
          float sp = (v > 20.f) ? v : log1pf(__expf(v));
          Cf[row * ldc + col] = sp;
        } else if constexpr (ACT == 4) {
          v += bias[col];
          float sp = (v > 20.f) ? v : log1pf(__expf(v));
          ((u16*)Cv)[row * ldc + col] = f2bf(sp);
        }
      }
}

// one fused fp32->bf16 convert for all weight/input tensors
__device__ __forceinline__ void cvt4(const float* __restrict__ in,
                                     u16* __restrict__ out, int i) {
  f32x4 v = ((const f32x4*)in)[i];
  us4 o;
  o[0] = f2bf(v[0]); o[1] = f2bf(v[1]); o[2] = f2bf(v[2]); o[3] = f2bf(v[3]);
  ((us4*)out)[i] = o;
}
__global__ __launch_bounds__(256) void cvt_all(
    const float* __restrict__ hs, const float* __restrict__ wIn,
    const float* __restrict__ wOut, const float* __restrict__ wDt,
    const float* __restrict__ wX, u16* __restrict__ Xb, u16* __restrict__ Winb,
    u16* __restrict__ Wob, u16* __restrict__ Wdtb, u16* __restrict__ Wxb) {
  int i = blockIdx.x * 256 + threadIdx.x;
  if (i < 2097152) { cvt4(hs, Xb, i); return; }
  i -= 2097152;
  if (i < 4194304) { cvt4(wIn, Winb, i); return; }
  i -= 4194304;
  if (i < 2097152) { cvt4(wOut, Wob, i); return; }
  i -= 2097152;
  if (i < 131072) { cvt4(wDt, Wdtb, i); return; }
  i -= 131072;
  if (i >= 262144) return;
  int row = (i << 2) >> 12;
  us4 o;
  if (row < 160) {
    f32x4 v = ((const f32x4*)wX)[i];
    o[0] = f2bf(v[0]); o[1] = f2bf(v[1]); o[2] = f2bf(v[2]); o[3] = f2bf(v[3]);
  } else {
    o[0] = 0; o[1] = 0; o[2] = 0; o[3] = 0;
  }
  ((us4*)Wxb)[i] = o;
}

// reduce 4 split-K partials of x_proj -> Smp fp32 (4096 x 256); also emit
// dt_r bf16 (first 128 cols).
__global__ __launch_bounds__(256) void xp_reduce(const float* __restrict__ part,
                                                 float* __restrict__ smp,
                                                 u16* __restrict__ dtrb) {
  int i = blockIdx.x * 256 + threadIdx.x;
  const f32x4* p = (const f32x4*)part;
  f32x4 v = p[i];
  v += p[i + 262144];
  v += p[i + 524288];
  v += p[i + 786432];
  ((f32x4*)smp)[i] = v;
  int e = i << 2;
  int c = e & 255;
  if (c < 128) {
    int t = e >> 8;
    us4 o;
    o[0] = f2bf(v[0]); o[1] = f2bf(v[1]); o[2] = f2bf(v[2]); o[3] = f2bf(v[3]);
    *(us4*)(dtrb + t * 128 + c) = o;
  }
}

// depthwise causal conv (K=4) + bias + SiLU
__global__ __launch_bounds__(256) void conv_silu(const u16* __restrict__ U,
                                                 const float* __restrict__ cw,
                                                 const float* __restrict__ cb,
                                                 u16* __restrict__ out) {
  int i = blockIdx.x * 256 + threadIdx.x;
  int t = i >> 10;
  int d4 = (i & 1023) << 2;
  int l = t & 2047;
  float w[4][4];
#pragma unroll
  for (int j = 0; j < 4; ++j) {
    f32x4 wv = *(const f32x4*)(cw + (d4 + j) * 4);
    w[j][0] = wv[0]; w[j][1] = wv[1]; w[j][2] = wv[2]; w[j][3] = wv[3];
  }
  float r[4] = {cb[d4], cb[d4 + 1], cb[d4 + 2], cb[d4 + 3]};
#pragma unroll
  for (int k = 0; k < 4; ++k) {
    int ll = l - 3 + k;
    if (ll >= 0) {
      us4 xv = *(const us4*)(U + (size_t)(t - 3 + k) * 4096 + d4);
      r[0] += w[0][k] * bf2f(xv[0]);
      r[1] += w[1][k] * bf2f(xv[1]);
      r[2] += w[2][k] * bf2f(xv[2]);
      r[3] += w[3][k] * bf2f(xv[3]);
    }
  }
  us4 o;
#pragma unroll
  for (int j = 0; j < 4; ++j) {
    float v = r[j];
    float s = v / (1.f + __expf(-v));
    o[j] = f2bf(s);
  }
  *(us4*)(out + (size_t)t * 4096 + d4) = o;
}

// ---------------------------------------------------------------------------
// Chunked selective scan, 32 chunks of 64 steps, channel-per-thread.
// ---------------------------------------------------------------------------
__global__ __launch_bounds__(256) void scan_part(
    const u16* __restrict__ dt, const u16* __restrict__ ub,
    const float* __restrict__ ssmp, const float* __restrict__ Alog,
    float* __restrict__ Sout, float* __restrict__ dtsumo) {
  const int tid = threadIdx.x;
  const int chunk = blockIdx.x, dgrp = blockIdx.y, b = blockIdx.z;
  const int d = (dgrp << 8) + tid;
  float A[16];
#pragma unroll
  for (int q = 0; q < 4; ++q) {
    f32x4 v = *(const f32x4*)(Alog + d * 16 + q * 4);
    A[q * 4 + 0] = -__expf(v[0]);
    A[q * 4 + 1] = -__expf(v[1]);
    A[q * 4 + 2] = -__expf(v[2]);
    A[q * 4 + 3] = -__expf(v[3]);
  }
  bool fastl = true;
#pragma unroll
  for (int n = 1; n < 16; ++n)
    fastl = fastl && (fabsf(A[n] - (n + 1) * A[0]) <= 1e-4f * (float)(n + 1));
  const bool fast = (__ballot(fastl) == ~0ull);

  const int base = b * 2048 + chunk * 64;
  const u16* dtp = dt + (size_t)base * 4096 + d;
  const u16* up = ub + (size_t)base * 4096 + d;
  const float* Bp = ssmp + (size_t)base * 256 + 128;

  float s[16] = {};
  float dtsum = 0.f;
  float cdt[8], cu[8], ndt[8] = {}, nu[8] = {};
#pragma unroll
  for (int j = 0; j < 8; ++j) {
    cdt[j] = bf2f(dtp[j * 4096]);
    cu[j] = bf2f(up[j * 4096]);
  }
  for (int l0 = 0; l0 < 64; l0 += 8) {
    if (l0 + 8 < 64) {
      int o = (l0 + 8) * 4096;
#pragma unroll
      for (int j = 0; j < 8; ++j) {
        ndt[j] = bf2f(dtp[o + j * 4096]);
        nu[j] = bf2f(up[o + j * 4096]);
      }
    }
    if (fast) {
#pragma unroll
      for (int j = 0; j < 8; ++j) {
        float e1 = __expf(cdt[j] * A[0]);
        float x = cdt[j] * cu[j];
        const float* Bl = Bp + (l0 + j) * 256;
        f32x4 B0 = *(const f32x4*)(Bl);
        f32x4 B1 = *(const f32x4*)(Bl + 4);
        f32x4 B2 = *(const f32x4*)(Bl + 8);
        f32x4 B3 = *(const f32x4*)(Bl + 12);
        float p = 1.f;
#pragma unroll
        for (int n = 0; n < 16; ++n) {
          p *= e1;
          float Bn = (n < 4) ? B0[n & 3] : (n < 8) ? B1[n & 3] : (n < 12) ? B2[n & 3] : B3[n & 3];
          s[n] = fmaf(p, s[n], x * Bn);
        }
        dtsum += cdt[j];
      }
    } else {
#pragma unroll
      for (int j = 0; j < 8; ++j) {
        float x = cdt[j] * cu[j];
        const float* Bl = Bp + (l0 + j) * 256;
        f32x4 B0 = *(const f32x4*)(Bl);
        f32x4 B1 = *(const f32x4*)(Bl + 4);
        f32x4 B2 = *(const f32x4*)(Bl + 8);
        f32x4 B3 = *(const f32x4*)(Bl + 12);
#pragma unroll
        for (int n = 0; n < 16; ++n) {
          float e = __expf(cdt[j] * A[n]);
          float Bn = (n < 4) ? B0[n & 3] : (n < 8) ? B1[n & 3] : (n < 12) ? B2[n & 3] : B3[n & 3];
          s[n] = fmaf(e, s[n], x * Bn);
        }
        dtsum += cdt[j];
      }
    }
#pragma unroll
    for (int j = 0; j < 8; ++j) { cdt[j] = ndt[j]; cu[j] = nu[j]; }
  }
  size_t o = ((size_t)(b * 32 + chunk) * 16) * 4096 + d;
#pragma unroll
  for (int n = 0; n < 16; ++n) Sout[o + (size_t)n * 4096] = s[n];
  dtsumo[(size_t)(b * 32 + chunk) * 4096 + d] = dtsum;
}

// prefix-fold chunk summaries: thread = (b, n, d); 32 serial chunks.
__global__ __launch_bounds__(256) void scan_fold(
    const float* __restrict__ Sin, const float* __restrict__ dtsum,
    const float* __restrict__ Alog, float* __restrict__ Sinit) {
  const int tid = threadIdx.x;
  const int n = blockIdx.x, dgrp = blockIdx.y, b = blockIdx.z;
  const int d = (dgrp << 8) + tid;
  const float A = -__expf(Alog[d * 16 + n]);
  float run = 0.f;
  for (int c = 0; c < 32; ++c) {
    size_t o = ((size_t)(b * 32 + c) * 16 + n) * 4096 + d;
    Sinit[o] = run;
    float P = __expf(dtsum[(size_t)(b * 32 + c) * 4096 + d] * A);
    run = fmaf(P, run, Sin[o]);
  }
}

__global__ __launch_bounds__(256) void scan_y(
    const u16* __restrict__ dt, const u16* __restrict__ ub,
    const float* __restrict__ ssmp, const u16* __restrict__ gs,
    const float* __restrict__ Alog, const float* __restrict__ Dv,
    const float* __restrict__ Sinit, u16* __restrict__ yb) {
  const int tid = threadIdx.x;
  const int chunk = blockIdx.x, dgrp = blockIdx.y, b = blockIdx.z;
  const int d = (dgrp << 8) + tid;
  float A[16];
#pragma unroll
  for (int q = 0; q < 4; ++q) {
    f32x4 v = *(const f32x4*)(Alog + d * 16 + q * 4);
    A[q * 4 + 0] = -__expf(v[0]);
    A[q * 4 + 1] = -__expf(v[1]);
    A[q * 4 + 2] = -__expf(v[2]);
    A[q * 4 + 3] = -__expf(v[3]);
  }
  bool fastl = true;
#pragma unroll
  for (int n = 1; n < 16; ++n)
    fastl = fastl && (fabsf(A[n] - (n + 1) * A[0]) <= 1e-4f * (float)(n + 1));
  const bool fast = (__ballot(fastl) == ~0ull);
  const float Dd = Dv[d];

  const int base = b * 2048 + chunk * 64;
  const u16* dtp = dt + (size_t)base * 4096 + d;
  const u16* up = ub + (size_t)base * 4096 + d;
  const u16* gp = gs + (size_t)base * 4096 + d;
  const float* Bp = ssmp + (size_t)base * 256 + 128;
  u16* yo = yb + (size_t)base * 4096 + d;

  float s[16];
  {
    size_t o = ((size_t)(b * 32 + chunk) * 16) * 4096 + d;
#pragma unroll
    for (int n = 0; n < 16; ++n) s[n] = Sinit[o + (size_t)n * 4096];
  }

  float cdt[8], cu[8], cg[8], ndt[8] = {}, nu[8] = {}, ng[8] = {};
#pragma unroll
  for (int j = 0; j < 8; ++j) {
    cdt[j] = bf2f(dtp[j * 4096]);
    cu[j] = bf2f(up[j * 4096]);
    cg[j] = bf2f(gp[j * 4096]);
  }
  for (int l0 = 0; l0 < 64; l0 += 8) {
    if (l0 + 8 < 64) {
      int o = (l0 + 8) * 4096;
#pragma unroll
      for (int j = 0; j < 8; ++j) {
        ndt[j] = bf2f(dtp[o + j * 4096]);
        nu[j] = bf2f(up[o + j * 4096]);
        ng[j] = bf2f(gp[o + j * 4096]);
      }
    }
    if (fast) {
#pragma unroll
      for (int j = 0; j < 8; ++j) {
        float e1 = __expf(cdt[j] * A[0]);
        float x = cdt[j] * cu[j];
        const float* Bl = Bp + (l0 + j) * 256;
        f32x4 B0 = *(const f32x4*)(Bl);
        f32x4 B1 = *(const f32x4*)(Bl + 4);
        f32x4 B2 = *(const f32x4*)(Bl + 8);
        f32x4 B3 = *(const f32x4*)(Bl + 12);
        f32x4 C0 = *(const f32x4*)(Bl + 16);
        f32x4 C1 = *(const f32x4*)(Bl + 20);
        f32x4 C2 = *(const f32x4*)(Bl + 24);
        f32x4 C3 = *(const f32x4*)(Bl + 28);
        float p = 1.f;
        float y0 = 0.f, y1 = 0.f, y2 = 0.f, y3 = 0.f;
#pragma unroll
        for (int n = 0; n < 16; ++n) {
          p *= e1;
          float Bn = (n < 4) ? B0[n & 3] : (n < 8) ? B1[n & 3] : (n < 12) ? B2[n & 3] : B3[n & 3];
          float Cn = (n < 4) ? C0[n & 3] : (n < 8) ? C1[n & 3] : (n < 12) ? C2[n & 3] : C3[n & 3];
          s[n] = fmaf(p, s[n], x * Bn);
          if (n < 4) y0 = fmaf(s[n], Cn, y0);
          else if (n < 8) y1 = fmaf(s[n], Cn, y1);
          else if (n < 12) y2 = fmaf(s[n], Cn, y2);
          else y3 = fmaf(s[n], Cn, y3);
        }
        float y = (y0 + y1) + (y2 + y3);
        yo[(l0 + j) * 4096] = f2bf((y + cu[j] * Dd) * cg[j]);
      }
    } else {
#pragma unroll
      for (int j = 0; j < 8; ++j) {
        float x = cdt[j] * cu[j];
        const float* Bl = Bp + (l0 + j) * 256;
        f32x4 B0 = *(const f32x4*)(Bl);
        f32x4 B1 = *(const f32x4*)(Bl + 4);
        f32x4 B2 = *(const f32x4*)(Bl + 8);
        f32x4 B3 = *(const f32x4*)(Bl + 12);
        f32x4 C0 = *(const f32x4*)(Bl + 16);
        f32x4 C1 = *(const f32x4*)(Bl + 20);
        f32x4 C2 = *(const f32x4*)(Bl + 24);
        f32x4 C3 = *(const f32x4*)(Bl + 28);
        float y0 = 0.f, y1 = 0.f, y2 = 0.f, y3 = 0.f;
#pragma unroll
        for (int n = 0; n < 16; ++n) {
          float e = __expf(cdt[j] * A[n]);
          float Bn = (n < 4) ? B0[n & 3] : (n < 8) ? B1[n & 3] : (n < 12) ? B2[n & 3] : B3[n & 3];
          float Cn = (n < 4) ? C0[n & 3] : (n < 8) ? C1[n & 3] : (n < 12) ? C2[n & 3] : C3[n & 3];
          s[n] = fmaf(e, s[n], x * Bn);
          if (n < 4) y0 = fmaf(s[n], Cn, y0);
          else if (n < 8) y1 = fmaf(s[n], Cn, y1);
          else if (n < 12) y2 = fmaf(s[n], Cn, y2);
          else y3 = fmaf(s[n], Cn, y3);
        }
        float y = (y0 + y1) + (y2 + y3);
        yo[(l0 + j) * 4096] = f2bf((y + cu[j] * Dd) * cg[j]);
      }
    }
#pragma unroll
    for (int j = 0; j < 8; ++j) { cdt[j] = ndt[j]; cu[j] = nu[j]; cg[j] = ng[j]; }
  }
}

extern "C" void kernel_launch(void* const* d_in, const int* in_sizes, int n_in,
                              void* d_out, int out_size, void* d_ws,
                              size_t ws_size, hipStream_t stream) {
  (void)in_sizes; (void)n_in; (void)out_size; (void)ws_size;
  const float* hs = (const float*)d_in[0];
  const float* wIn = (const float*)d_in[1];
  const float* cw = (const float*)d_in[2];
  const float* cb = (const float*)d_in[3];
  const float* wX = (const float*)d_in[4];
  const float* wDt = (const float*)d_in[5];
  const float* bDt = (const float*)d_in[6];
  const float* Alog = (const float*)d_in[7];
  const float* Dv = (const float*)d_in[8];
  const float* wOut = (const float*)d_in[9];

  // ---- workspace layout (peak 185 MB) -------------------------------------
  const size_t MB = 1ull << 20;
  char* w = (char*)d_ws;
  u16* Xb = (u16*)(w + 0 * MB);
  u16* Winb = (u16*)(w + 16 * MB);
  u16* Pu = (u16*)(w + 48 * MB);
  u16* Dtb = (u16*)(w + 0 * MB);
  u16* Yb = (u16*)(w + 64 * MB);
  u16* Ub = (u16*)(w + 96 * MB);
  u16* Wxb = (u16*)(w + 128 * MB);
  float* Smp = (float*)(w + 130 * MB);
  u16* Dtrb = (u16*)(w + 134 * MB);
  u16* Wdtb = (u16*)(w + 135 * MB);
  u16* Wob = (u16*)(w + 136 * MB);
  float* Schk = (float*)(w + 152 * MB);
  float* Xpart = (float*)(w + 152 * MB);  // alias: dead before Schk written
  float* Sinit = (float*)(w + 168 * MB);
  float* Dtsum = (float*)(w + 184 * MB);
  u16* Pg = (u16*)d_out;

  cvt_all<<<34304, 256, 0, stream>>>(hs, wIn, wOut, wDt, wX, Xb, Winb, Wob, Wdtb, Wxb);
  gemm256<<<dim3(32, 16), 512, 0, stream>>>(Xb, Winb, Pu, Pg, 2048);
  conv_silu<<<16384, 256, 0, stream>>>(Pu, cw, cb, Ub);
  gemm_bt<0, true><<<dim3(2, 32, 4), 256, 0, stream>>>(Ub, Wxb, Xpart, nullptr, 4096, 256);
  xp_reduce<<<1024, 256, 0, stream>>>(Xpart, Smp, Dtrb);
  gemm_bt<4><<<dim3(32, 32), 256, 0, stream>>>(Dtrb, Wdtb, Dtb, bDt, 128, 4096);
  scan_part<<<dim3(32, 16, 2), 256, 0, stream>>>(Dtb, Ub, Smp, Alog, Schk, Dtsum);
  scan_fold<<<dim3(16, 16, 2), 256, 0, stream>>>(Schk, Dtsum, Alog, Sinit);
  scan_y<<<dim3(32, 16, 2), 256, 0, stream>>>(Dtb, Ub, Smp, Pg, Alog, Dv, Sinit, Yb);
  gemm_bt<0><<<dim3(16, 32), 256, 0, stream>>>(Yb, Wob, (float*)d_out, nullptr, 4096, 2048);
}

// Round 5
// 621.630 us; speedup vs baseline: 1.2702x; 1.2702x over previous
//
#include <hip/hip_runtime.h>

typedef unsigned int u32;
typedef unsigned short u16;
typedef float f32x4 __attribute__((ext_vector_type(4)));
typedef float f32x16 __attribute__((ext_vector_type(16)));
typedef u16 us4 __attribute__((ext_vector_type(4)));
typedef u16 us8 __attribute__((ext_vector_type(8)));
typedef __bf16 bf16x8 __attribute__((ext_vector_type(8)));

__device__ __forceinline__ u16 f2bf(float f) {
  u32 u = __builtin_bit_cast(u32, f);
  u += 0x7fffu + ((u >> 16) & 1u);
  return (u16)(u >> 16);
}
__device__ __forceinline__ float bf2f(u16 h) {
  u32 u = ((u32)h) << 16;
  return __builtin_bit_cast(float, u);
}
__device__ __forceinline__ void async16(const void* g, void* l) {
  __builtin_amdgcn_global_load_lds((const __attribute__((address_space(1))) void*)g,
                                   (__attribute__((address_space(3))) void*)l, 16, 0, 0);
}

// ---------------------------------------------------------------------------
// gemm256: 256x256 tile, BK=64, 8 waves (2M x 4N), 8-phase counted-vmcnt
// schedule (T3+T4), XOR-4 LDS swizzle (T2, 0 conflicts R2/R3), setprio (T5),
// XCD col-partitioned mapping (T1; R3: FETCH 270->98MB = ideal).
// C = A * B^T.  Phase = (set, ks, mh): one M-half quadrant x one K-half:
// 4 A ds_reads (+4 B ds_reads on mh=0, reused for mh=1), 16 MFMA.
//
// R4 post-mortem: removing the post-barrier lgkmcnt(0)+sched_barrier(0) was
// neutral-to-negative (MfmaUtil 38->31) -- the m201 template's fence is
// load-bearing; RESTORED.  R5 change: barriers are now
// __builtin_amdgcn_s_barrier() (no memory clobber), m201-mechanical form.
// The asm s_waitcnt (with "memory") remain the ONLY memory fences, so:
//  - ds_reads cannot hoist above the vmcnt wait that guarantees their piece
//    landed (p0/p1 covered by end-p5 vm8, p2/p3 by end-p7, p4/p5 by next
//    end-p1, p6/p7 by next end-p3);
//  - gload_lds issues cannot cross any vmcnt wait (positional counting safe);
//  - gload_lds vs ds_read on As/Bs may-alias (runtime XOR offsets) so
//    write-after-read order is preserved.
// The scheduler may now float next-phase ds_reads / stage-issues into the
// current MFMA cluster -- the cross-phase overlap the template relies on.
//
// Staging windows:
//   p0: stage As1.K1(t1)   p1: Bs1.K1(t1)  vm8   (read p6/p7)
//   p2: stage As0.K0(t2)   p3: Bs0.K0(t2)  vm8   (read next p0/p1)
//   p4: stage As0.K1(t2)   p5: Bs0.K1(t2)  vm8   (read next p2/p3)
//   p6: stage As1.K0(t3)   p7: Bs1.K0(t3)  vm8   (read next p4/p5)
// Last iter: p0/p1 stage only; waits peel vm8 / vm4 / vm0.
// ---------------------------------------------------------------------------
#define STG(GP, LP, OFF, KOFF)                              \
  {                                                         \
    async16((GP) + (KOFF), (LP) + (OFF));                   \
    async16((GP) + 128L * K + (KOFF), (LP) + (OFF) + 4096); \
  }

#define PHASE(SET, KS, MH, STAGE_STMT, TAIL_STMT)                               \
  {                                                                             \
    const u16* Ap_ = As + (SET) * 16384 + (KS) * 8192;                          \
    const u16* Bp_ = Bs + (SET) * 16384 + (KS) * 8192;                          \
    us8 af0 = *(const us8*)(Ap_ + ra[(MH) * 4 + 0]);                            \
    us8 af1 = *(const us8*)(Ap_ + ra[(MH) * 4 + 1]);                            \
    us8 af2 = *(const us8*)(Ap_ + ra[(MH) * 4 + 2]);                            \
    us8 af3 = *(const us8*)(Ap_ + ra[(MH) * 4 + 3]);                            \
    if ((MH) == 0) {                                                            \
      _Pragma("unroll") for (int nf = 0; nf < 4; ++nf)                          \
          bfr[nf] = *(const us8*)(Bp_ + rb[nf]);                                \
    }                                                                           \
    STAGE_STMT;                                                                 \
    __builtin_amdgcn_s_barrier();                                               \
    asm volatile("s_waitcnt lgkmcnt(0)" ::: "memory");                          \
    __builtin_amdgcn_sched_barrier(0);                                          \
    __builtin_amdgcn_s_setprio(1);                                              \
    _Pragma("unroll") for (int nf = 0; nf < 4; ++nf) {                          \
      acc[(MH) * 4 + 0][nf] = __builtin_amdgcn_mfma_f32_16x16x32_bf16(          \
          __builtin_bit_cast(bf16x8, af0), __builtin_bit_cast(bf16x8, bfr[nf]), \
          acc[(MH) * 4 + 0][nf], 0, 0, 0);                                      \
      acc[(MH) * 4 + 1][nf] = __builtin_amdgcn_mfma_f32_16x16x32_bf16(          \
          __builtin_bit_cast(bf16x8, af1), __builtin_bit_cast(bf16x8, bfr[nf]), \
          acc[(MH) * 4 + 1][nf], 0, 0, 0);                                      \
      acc[(MH) * 4 + 2][nf] = __builtin_amdgcn_mfma_f32_16x16x32_bf16(          \
          __builtin_bit_cast(bf16x8, af2), __builtin_bit_cast(bf16x8, bfr[nf]), \
          acc[(MH) * 4 + 2][nf], 0, 0, 0);                                      \
      acc[(MH) * 4 + 3][nf] = __builtin_amdgcn_mfma_f32_16x16x32_bf16(          \
          __builtin_bit_cast(bf16x8, af3), __builtin_bit_cast(bf16x8, bfr[nf]), \
          acc[(MH) * 4 + 3][nf], 0, 0, 0);                                      \
    }                                                                           \
    __builtin_amdgcn_s_setprio(0);                                              \
    TAIL_STMT;                                                                  \
    __builtin_amdgcn_s_barrier();                                               \
  }

__global__ __launch_bounds__(512, 2) void gemm256(const u16* __restrict__ A,
                                                  const u16* __restrict__ B,
                                                  u16* __restrict__ U,
                                                  u16* __restrict__ G, int K) {
  __shared__ __align__(16) u16 As[32768];  // 2 sets x 2 K-halves x 256x32
  __shared__ __align__(16) u16 Bs[32768];
  const int tid = threadIdx.x;
  const int lane = tid & 63;
  const int wave = tid >> 6;
  const int wm = wave >> 2;  // 0..1 : 128-row block
  const int wn = wave & 3;   // 0..3 : 64-col block
  const int l15 = lane & 15;
  const int kc2 = lane >> 4;                // chunk within K-half
  const int pc2s = kc2 ^ ((l15 >> 1) & 3);  // XOR-4 swizzle (read side)

  // XCD-aware mapping from true dispatch order (x fastest).
  const int nbx = (int)gridDim.x;  // col tiles (32)
  const int d = (int)blockIdx.y * nbx + (int)blockIdx.x;
  const int cpn = nbx >> 3;        // cols per XCD (4)
  const int xcd = d & 7;
  const int s = d >> 3;
  const long colBase = (long)(xcd * cpn + (s % cpn)) << 8;
  const long rowBase = (long)(s / cpn) << 8;

  // staging: thread covers tile row (tid>>2)(+128), swizzled chunk of 8.
  const int c0 = ((tid & 3) ^ ((tid >> 3) & 3)) << 3;
  const u16* Ag = A + (rowBase + (tid >> 2)) * (long)K + c0;
  const u16* Bg = B + (colBase + (tid >> 2)) * (long)K + c0;
  u16* Alds = As + tid * 8;
  u16* Blds = Bs + tid * 8;

  int ra[8], rb[4];
#pragma unroll
  for (int mf = 0; mf < 8; ++mf)
    ra[mf] = (wm * 128 + mf * 16 + l15) * 32 + pc2s * 8;
#pragma unroll
  for (int nf = 0; nf < 4; ++nf)
    rb[nf] = (wn * 64 + nf * 16 + l15) * 32 + pc2s * 8;

  f32x4 acc[8][4] = {};
  us8 bfr[4];

  // prologue: tile0 (both K-halves) + tile1.K0
  STG(Ag, Alds, 0, 0);
  STG(Bg, Blds, 0, 0);
  STG(Ag, Alds, 8192, 32);
  STG(Bg, Blds, 8192, 32);
  STG(Ag, Alds, 16384, 64);
  STG(Bg, Blds, 16384, 64);
  asm volatile("s_waitcnt vmcnt(4)" ::: "memory");
  __builtin_amdgcn_s_barrier();

  const int nIter = K >> 7;
  for (int t = 0; t < nIter; ++t) {
    const int k1 = (2 * t + 1) * 64;
    const int k2 = (2 * t + 2) * 64;
    const int k3 = (2 * t + 3) * 64;
    const bool full = (t < nIter - 1);
    PHASE(0, 0, 0, { STG(Ag, Alds, 24576, k1 + 32); }, {});
    PHASE(0, 0, 1, { STG(Bg, Blds, 24576, k1 + 32); },
          { asm volatile("s_waitcnt vmcnt(8)" ::: "memory"); });
    PHASE(0, 1, 0, { if (full) STG(Ag, Alds, 0, k2); }, {});
    PHASE(0, 1, 1, { if (full) STG(Bg, Blds, 0, k2); },
          {
            if (full) asm volatile("s_waitcnt vmcnt(8)" ::: "memory");
            else asm volatile("s_waitcnt vmcnt(4)" ::: "memory");
          });
    PHASE(1, 0, 0, { if (full) STG(Ag, Alds, 8192, k2 + 32); }, {});
    PHASE(1, 0, 1, { if (full) STG(Bg, Blds, 8192, k2 + 32); },
          {
            if (full) asm volatile("s_waitcnt vmcnt(8)" ::: "memory");
            else asm volatile("s_waitcnt vmcnt(0)" ::: "memory");
          });
    PHASE(1, 1, 0, { if (full) STG(Ag, Alds, 16384, k3); }, {});
    PHASE(1, 1, 1, { if (full) STG(Bg, Blds, 16384, k3); },
          { if (full) asm volatile("s_waitcnt vmcnt(8)" ::: "memory"); });
  }

  // epilogue: C/D 16x16 layout col=lane&15, row=(lane>>4)*4+reg  [m89]
  const int gate = (colBase >= 4096);
  u16* Out = gate ? G : U;
  const long cb = gate ? (colBase - 4096) : colBase;
#pragma unroll
  for (int mf = 0; mf < 8; ++mf) {
    long row0 = rowBase + wm * 128 + mf * 16 + (lane >> 4) * 4;
#pragma unroll
    for (int nf = 0; nf < 4; ++nf) {
      long col = cb + wn * 64 + nf * 16 + l15;
#pragma unroll
      for (int r = 0; r < 4; ++r) {
        float v = acc[mf][nf][r];
        if (gate) v = v / (1.f + __expf(-v));
        Out[(row0 + r) * 4096 + col] = f2bf(v);
      }
    }
  }
}

// ---------------------------------------------------------------------------
// C = A * B^T.  A: M x K bf16 row-major. B: N x K bf16 row-major.
// BK=64, XOR-8 swizzled LDS (conflict-free, verified r7), 32x32x16 MFMA.
// A/B frag: [m|n = lane&31][k = 8*(lane>>5) + j]; C/D: col=lane&31,
// row=(reg&3)+8*(reg>>2)+4*(lane>>5)  [m74/m101].
// ACT: 0 fp32, 3 fp32 softplus(+bias), 4 bf16 softplus(+bias).
// SPLITK: blockIdx.z K-slice, C offset per z.
// ---------------------------------------------------------------------------
template <int ACT, bool SPLITK = false>
__global__ __launch_bounds__(256) void gemm_bt(const u16* __restrict__ A,
                                               const u16* __restrict__ B,
                                               void* __restrict__ Cv,
                                               const float* __restrict__ bias,
                                               int K, int ldc) {
  __shared__ __align__(16) u16 As[128 * 64];
  __shared__ __align__(16) u16 Bs[128 * 64];
  const int tid = threadIdx.x;
  const int lane = tid & 63;
  const int wave = tid >> 6;
  const int ln = lane & 31;   // m/n within 32-tile
  const int hw = lane >> 5;   // half-wave k selector
  const int wm = (wave >> 1) << 6;
  const int wn = (wave & 1) << 6;
  const long rowBase = (long)blockIdx.y << 7;
  const long colBase = (long)blockIdx.x << 7;

  int kStart = 0, kEnd = K;
  if constexpr (SPLITK) {
    int kn = K / gridDim.z;
    kStart = blockIdx.z * kn;
    kEnd = kStart + kn;
  }

  const int rr = tid >> 3;
  const int qg = (tid & 7) ^ (rr & 7);
  const u16* Ag = A + (rowBase + rr) * (long)K + qg * 8;
  const u16* Bg = B + (colBase + rr) * (long)K + qg * 8;
  u16* Al = As + tid * 8;
  u16* Bl = Bs + tid * 8;

  f32x16 acc[2][2] = {};
  const int l7 = ln & 7;

  for (int k0 = kStart; k0 < kEnd; k0 += 64) {
#pragma unroll
    for (int c = 0; c < 4; ++c) {
      async16(Ag + 32L * c * K + k0, Al + 2048 * c);
      async16(Bg + 32L * c * K + k0, Bl + 2048 * c);
    }
    __syncthreads();
#pragma unroll
    for (int s = 0; s < 4; ++s) {  // K=16 slice; chunk pair {2s, 2s+1}
      const int xa = ((s * 2 + hw) ^ l7) * 8;
      us8 af[2], bfr[2];
#pragma unroll
      for (int i = 0; i < 2; ++i)
        af[i] = *(const us8*)(As + (wm + i * 32 + ln) * 64 + xa);
#pragma unroll
      for (int i = 0; i < 2; ++i)
        bfr[i] = *(const us8*)(Bs + (wn + i * 32 + ln) * 64 + xa);
#pragma unroll
      for (int i = 0; i < 2; ++i)
#pragma unroll
        for (int j = 0; j < 2; ++j)
          acc[i][j] = __builtin_amdgcn_mfma_f32_32x32x16_bf16(
              __builtin_bit_cast(bf16x8, af[i]), __builtin_bit_cast(bf16x8, bfr[j]),
              acc[i][j], 0, 0, 0);
    }
    __syncthreads();
  }

  float* Cf = (float*)Cv;
  if constexpr (SPLITK)
    Cf += (size_t)blockIdx.z * ((size_t)gridDim.y * 128 * ldc);

#pragma unroll
  for (int i = 0; i < 2; ++i)
#pragma unroll
    for (int j = 0; j < 2; ++j)
#pragma unroll
      for (int r = 0; r < 16; ++r) {
        long row = rowBase + wm + i * 32 + (r & 3) + 8 * (r >> 2) + 4 * hw;
        long col = colBase + wn + j * 32 + ln;
        float v = acc[i][j][r];
        if constexpr (ACT == 0) {
          Cf[row * ldc + col] = v;
        } else if constexpr (ACT == 3) {
          v += bias[col];
          float sp = (v > 20.f) ? v : log1pf(__expf(v));
          Cf[row * ldc + col] = sp;
        } else if constexpr (ACT == 4) {
          v += bias[col];
          float sp = (v > 20.f) ? v : log1pf(__expf(v));
          ((u16*)Cv)[row * ldc + col] = f2bf(sp);
        }
      }
}

// one fused fp32->bf16 convert for all weight/input tensors
__device__ __forceinline__ void cvt4(const float* __restrict__ in,
                                     u16* __restrict__ out, int i) {
  f32x4 v = ((const f32x4*)in)[i];
  us4 o;
  o[0] = f2bf(v[0]); o[1] = f2bf(v[1]); o[2] = f2bf(v[2]); o[3] = f2bf(v[3]);
  ((us4*)out)[i] = o;
}
__global__ __launch_bounds__(256) void cvt_all(
    const float* __restrict__ hs, const float* __restrict__ wIn,
    const float* __restrict__ wOut, const float* __restrict__ wDt,
    const float* __restrict__ wX, u16* __restrict__ Xb, u16* __restrict__ Winb,
    u16* __restrict__ Wob, u16* __restrict__ Wdtb, u16* __restrict__ Wxb) {
  int i = blockIdx.x * 256 + threadIdx.x;
  if (i < 2097152) { cvt4(hs, Xb, i); return; }
  i -= 2097152;
  if (i < 4194304) { cvt4(wIn, Winb, i); return; }
  i -= 4194304;
  if (i < 2097152) { cvt4(wOut, Wob, i); return; }
  i -= 2097152;
  if (i < 131072) { cvt4(wDt, Wdtb, i); return; }
  i -= 131072;
  if (i >= 262144) return;
  int row = (i << 2) >> 12;
  us4 o;
  if (row < 160) {
    f32x4 v = ((const f32x4*)wX)[i];
    o[0] = f2bf(v[0]); o[1] = f2bf(v[1]); o[2] = f2bf(v[2]); o[3] = f2bf(v[3]);
  } else {
    o[0] = 0; o[1] = 0; o[2] = 0; o[3] = 0;
  }
  ((us4*)Wxb)[i] = o;
}

// reduce 4 split-K partials of x_proj -> Smp fp32 (4096 x 256); also emit
// dt_r bf16 (first 128 cols).
__global__ __launch_bounds__(256) void xp_reduce(const float* __restrict__ part,
                                                 float* __restrict__ smp,
                                                 u16* __restrict__ dtrb) {
  int i = blockIdx.x * 256 + threadIdx.x;
  const f32x4* p = (const f32x4*)part;
  f32x4 v = p[i];
  v += p[i + 262144];
  v += p[i + 524288];
  v += p[i + 786432];
  ((f32x4*)smp)[i] = v;
  int e = i << 2;
  int c = e & 255;
  if (c < 128) {
    int t = e >> 8;
    us4 o;
    o[0] = f2bf(v[0]); o[1] = f2bf(v[1]); o[2] = f2bf(v[2]); o[3] = f2bf(v[3]);
    *(us4*)(dtrb + t * 128 + c) = o;
  }
}

// depthwise causal conv (K=4) + bias + SiLU
__global__ __launch_bounds__(256) void conv_silu(const u16* __restrict__ U,
                                                 const float* __restrict__ cw,
                                                 const float* __restrict__ cb,
                                                 u16* __restrict__ out) {
  int i = blockIdx.x * 256 + threadIdx.x;
  int t = i >> 10;
  int d4 = (i & 1023) << 2;
  int l = t & 2047;
  float w[4][4];
#pragma unroll
  for (int j = 0; j < 4; ++j) {
    f32x4 wv = *(const f32x4*)(cw + (d4 + j) * 4);
    w[j][0] = wv[0]; w[j][1] = wv[1]; w[j][2] = wv[2]; w[j][3] = wv[3];
  }
  float r[4] = {cb[d4], cb[d4 + 1], cb[d4 + 2], cb[d4 + 3]};
#pragma unroll
  for (int k = 0; k < 4; ++k) {
    int ll = l - 3 + k;
    if (ll >= 0) {
      us4 xv = *(const us4*)(U + (size_t)(t - 3 + k) * 4096 + d4);
      r[0] += w[0][k] * bf2f(xv[0]);
      r[1] += w[1][k] * bf2f(xv[1]);
      r[2] += w[2][k] * bf2f(xv[2]);
      r[3] += w[3][k] * bf2f(xv[3]);
    }
  }
  us4 o;
#pragma unroll
  for (int j = 0; j < 4; ++j) {
    float v = r[j];
    float s = v / (1.f + __expf(-v));
    o[j] = f2bf(s);
  }
  *(us4*)(out + (size_t)t * 4096 + d4) = o;
}

// ---------------------------------------------------------------------------
// Chunked selective scan, 32 chunks of 64 steps, channel-per-thread.
// ---------------------------------------------------------------------------
__global__ __launch_bounds__(256) void scan_part(
    const u16* __restrict__ dt, const u16* __restrict__ ub,
    const float* __restrict__ ssmp, const float* __restrict__ Alog,
    float* __restrict__ Sout, float* __restrict__ dtsumo) {
  const int tid = threadIdx.x;
  const int chunk = blockIdx.x, dgrp = blockIdx.y, b = blockIdx.z;
  const int d = (dgrp << 8) + tid;
  float A[16];
#pragma unroll
  for (int q = 0; q < 4; ++q) {
    f32x4 v = *(const f32x4*)(Alog + d * 16 + q * 4);
    A[q * 4 + 0] = -__expf(v[0]);
    A[q * 4 + 1] = -__expf(v[1]);
    A[q * 4 + 2] = -__expf(v[2]);
    A[q * 4 + 3] = -__expf(v[3]);
  }
  bool fastl = true;
#pragma unroll
  for (int n = 1; n < 16; ++n)
    fastl = fastl && (fabsf(A[n] - (n + 1) * A[0]) <= 1e-4f * (float)(n + 1));
  const bool fast = (__ballot(fastl) == ~0ull);

  const int base = b * 2048 + chunk * 64;
  const u16* dtp = dt + (size_t)base * 4096 + d;
  const u16* up = ub + (size_t)base * 4096 + d;
  const float* Bp = ssmp + (size_t)base * 256 + 128;

  float s[16] = {};
  float dtsum = 0.f;
  float cdt[8], cu[8], ndt[8] = {}, nu[8] = {};
#pragma unroll
  for (int j = 0; j < 8; ++j) {
    cdt[j] = bf2f(dtp[j * 4096]);
    cu[j] = bf2f(up[j * 4096]);
  }
  for (int l0 = 0; l0 < 64; l0 += 8) {
    if (l0 + 8 < 64) {
      int o = (l0 + 8) * 4096;
#pragma unroll
      for (int j = 0; j < 8; ++j) {
        ndt[j] = bf2f(dtp[o + j * 4096]);
        nu[j] = bf2f(up[o + j * 4096]);
      }
    }
    if (fast) {
#pragma unroll
      for (int j = 0; j < 8; ++j) {
        float e1 = __expf(cdt[j] * A[0]);
        float x = cdt[j] * cu[j];
        const float* Bl = Bp + (l0 + j) * 256;
        f32x4 B0 = *(const f32x4*)(Bl);
        f32x4 B1 = *(const f32x4*)(Bl + 4);
        f32x4 B2 = *(const f32x4*)(Bl + 8);
        f32x4 B3 = *(const f32x4*)(Bl + 12);
        float p = 1.f;
#pragma unroll
        for (int n = 0; n < 16; ++n) {
          p *= e1;
          float Bn = (n < 4) ? B0[n & 3] : (n < 8) ? B1[n & 3] : (n < 12) ? B2[n & 3] : B3[n & 3];
          s[n] = fmaf(p, s[n], x * Bn);
        }
        dtsum += cdt[j];
      }
    } else {
#pragma unroll
      for (int j = 0; j < 8; ++j) {
        float x = cdt[j] * cu[j];
        const float* Bl = Bp + (l0 + j) * 256;
        f32x4 B0 = *(const f32x4*)(Bl);
        f32x4 B1 = *(const f32x4*)(Bl + 4);
        f32x4 B2 = *(const f32x4*)(Bl + 8);
        f32x4 B3 = *(const f32x4*)(Bl + 12);
#pragma unroll
        for (int n = 0; n < 16; ++n) {
          float e = __expf(cdt[j] * A[n]);
          float Bn = (n < 4) ? B0[n & 3] : (n < 8) ? B1[n & 3] : (n < 12) ? B2[n & 3] : B3[n & 3];
          s[n] = fmaf(e, s[n], x * Bn);
        }
        dtsum += cdt[j];
      }
    }
#pragma unroll
    for (int j = 0; j < 8; ++j) { cdt[j] = ndt[j]; cu[j] = nu[j]; }
  }
  size_t o = ((size_t)(b * 32 + chunk) * 16) * 4096 + d;
#pragma unroll
  for (int n = 0; n < 16; ++n) Sout[o + (size_t)n * 4096] = s[n];
  dtsumo[(size_t)(b * 32 + chunk) * 4096 + d] = dtsum;
}

// prefix-fold chunk summaries: thread = (b, n, d); 32 serial chunks.
__global__ __launch_bounds__(256) void scan_fold(
    const float* __restrict__ Sin, const float* __restrict__ dtsum,
    const float* __restrict__ Alog, float* __restrict__ Sinit) {
  const int tid = threadIdx.x;
  const int n = blockIdx.x, dgrp = blockIdx.y, b = blockIdx.z;
  const int d = (dgrp << 8) + tid;
  const float A = -__expf(Alog[d * 16 + n]);
  float run = 0.f;
  for (int c = 0; c < 32; ++c) {
    size_t o = ((size_t)(b * 32 + c) * 16 + n) * 4096 + d;
    Sinit[o] = run;
    float P = __expf(dtsum[(size_t)(b * 32 + c) * 4096 + d] * A);
    run = fmaf(P, run, Sin[o]);
  }
}

__global__ __launch_bounds__(256) void scan_y(
    const u16* __restrict__ dt, const u16* __restrict__ ub,
    const float* __restrict__ ssmp, const u16* __restrict__ gs,
    const float* __restrict__ Alog, const float* __restrict__ Dv,
    const float* __restrict__ Sinit, u16* __restrict__ yb) {
  const int tid = threadIdx.x;
  const int chunk = blockIdx.x, dgrp = blockIdx.y, b = blockIdx.z;
  const int d = (dgrp << 8) + tid;
  float A[16];
#pragma unroll
  for (int q = 0; q < 4; ++q) {
    f32x4 v = *(const f32x4*)(Alog + d * 16 + q * 4);
    A[q * 4 + 0] = -__expf(v[0]);
    A[q * 4 + 1] = -__expf(v[1]);
    A[q * 4 + 2] = -__expf(v[2]);
    A[q * 4 + 3] = -__expf(v[3]);
  }
  bool fastl = true;
#pragma unroll
  for (int n = 1; n < 16; ++n)
    fastl = fastl && (fabsf(A[n] - (n + 1) * A[0]) <= 1e-4f * (float)(n + 1));
  const bool fast = (__ballot(fastl) == ~0ull);
  const float Dd = Dv[d];

  const int base = b * 2048 + chunk * 64;
  const u16* dtp = dt + (size_t)base * 4096 + d;
  const u16* up = ub + (size_t)base * 4096 + d;
  const u16* gp = gs + (size_t)base * 4096 + d;
  const float* Bp = ssmp + (size_t)base * 256 + 128;
  u16* yo = yb + (size_t)base * 4096 + d;

  float s[16];
  {
    size_t o = ((size_t)(b * 32 + chunk) * 16) * 4096 + d;
#pragma unroll
    for (int n = 0; n < 16; ++n) s[n] = Sinit[o + (size_t)n * 4096];
  }

  float cdt[8], cu[8], cg[8], ndt[8] = {}, nu[8] = {}, ng[8] = {};
#pragma unroll
  for (int j = 0; j < 8; ++j) {
    cdt[j] = bf2f(dtp[j * 4096]);
    cu[j] = bf2f(up[j * 4096]);
    cg[j] = bf2f(gp[j * 4096]);
  }
  for (int l0 = 0; l0 < 64; l0 += 8) {
    if (l0 + 8 < 64) {
      int o = (l0 + 8) * 4096;
#pragma unroll
      for (int j = 0; j < 8; ++j) {
        ndt[j] = bf2f(dtp[o + j * 4096]);
        nu[j] = bf2f(up[o + j * 4096]);
        ng[j] = bf2f(gp[o + j * 4096]);
      }
    }
    if (fast) {
#pragma unroll
      for (int j = 0; j < 8; ++j) {
        float e1 = __expf(cdt[j] * A[0]);
        float x = cdt[j] * cu[j];
        const float* Bl = Bp + (l0 + j) * 256;
        f32x4 B0 = *(const f32x4*)(Bl);
        f32x4 B1 = *(const f32x4*)(Bl + 4);
        f32x4 B2 = *(const f32x4*)(Bl + 8);
        f32x4 B3 = *(const f32x4*)(Bl + 12);
        f32x4 C0 = *(const f32x4*)(Bl + 16);
        f32x4 C1 = *(const f32x4*)(Bl + 20);
        f32x4 C2 = *(const f32x4*)(Bl + 24);
        f32x4 C3 = *(const f32x4*)(Bl + 28);
        float p = 1.f;
        float y0 = 0.f, y1 = 0.f, y2 = 0.f, y3 = 0.f;
#pragma unroll
        for (int n = 0; n < 16; ++n) {
          p *= e1;
          float Bn = (n < 4) ? B0[n & 3] : (n < 8) ? B1[n & 3] : (n < 12) ? B2[n & 3] : B3[n & 3];
          float Cn = (n < 4) ? C0[n & 3] : (n < 8) ? C1[n & 3] : (n < 12) ? C2[n & 3] : C3[n & 3];
          s[n] = fmaf(p, s[n], x * Bn);
          if (n < 4) y0 = fmaf(s[n], Cn, y0);
          else if (n < 8) y1 = fmaf(s[n], Cn, y1);
          else if (n < 12) y2 = fmaf(s[n], Cn, y2);
          else y3 = fmaf(s[n], Cn, y3);
        }
        float y = (y0 + y1) + (y2 + y3);
        yo[(l0 + j) * 4096] = f2bf((y + cu[j] * Dd) * cg[j]);
      }
    } else {
#pragma unroll
      for (int j = 0; j < 8; ++j) {
        float x = cdt[j] * cu[j];
        const float* Bl = Bp + (l0 + j) * 256;
        f32x4 B0 = *(const f32x4*)(Bl);
        f32x4 B1 = *(const f32x4*)(Bl + 4);
        f32x4 B2 = *(const f32x4*)(Bl + 8);
        f32x4 B3 = *(const f32x4*)(Bl + 12);
        f32x4 C0 = *(const f32x4*)(Bl + 16);
        f32x4 C1 = *(const f32x4*)(Bl + 20);
        f32x4 C2 = *(const f32x4*)(Bl + 24);
        f32x4 C3 = *(const f32x4*)(Bl + 28);
        float y0 = 0.f, y1 = 0.f, y2 = 0.f, y3 = 0.f;
#pragma unroll
        for (int n = 0; n < 16; ++n) {
          float e = __expf(cdt[j] * A[n]);
          float Bn = (n < 4) ? B0[n & 3] : (n < 8) ? B1[n & 3] : (n < 12) ? B2[n & 3] : B3[n & 3];
          float Cn = (n < 4) ? C0[n & 3] : (n < 8) ? C1[n & 3] : (n < 12) ? C2[n & 3] : C3[n & 3];
          s[n] = fmaf(e, s[n], x * Bn);
          if (n < 4) y0 = fmaf(s[n], Cn, y0);
          else if (n < 8) y1 = fmaf(s[n], Cn, y1);
          else if (n < 12) y2 = fmaf(s[n], Cn, y2);
          else y3 = fmaf(s[n], Cn, y3);
        }
        float y = (y0 + y1) + (y2 + y3);
        yo[(l0 + j) * 4096] = f2bf((y + cu[j] * Dd) * cg[j]);
      }
    }
#pragma unroll
    for (int j = 0; j < 8; ++j) { cdt[j] = ndt[j]; cu[j] = nu[j]; cg[j] = ng[j]; }
  }
}

extern "C" void kernel_launch(void* const* d_in, const int* in_sizes, int n_in,
                              void* d_out, int out_size, void* d_ws,
                              size_t ws_size, hipStream_t stream) {
  (void)in_sizes; (void)n_in; (void)out_size; (void)ws_size;
  const float* hs = (const float*)d_in[0];
  const float* wIn = (const float*)d_in[1];
  const float* cw = (const float*)d_in[2];
  const float* cb = (const float*)d_in[3];
  const float* wX = (const float*)d_in[4];
  const float* wDt = (const float*)d_in[5];
  const float* bDt = (const float*)d_in[6];
  const float* Alog = (const float*)d_in[7];
  const float* Dv = (const float*)d_in[8];
  const float* wOut = (const float*)d_in[9];

  // ---- workspace layout (peak 185 MB) -------------------------------------
  const size_t MB = 1ull << 20;
  char* w = (char*)d_ws;
  u16* Xb = (u16*)(w + 0 * MB);
  u16* Winb = (u16*)(w + 16 * MB);
  u16* Pu = (u16*)(w + 48 * MB);
  u16* Dtb = (u16*)(w + 0 * MB);
  u16* Yb = (u16*)(w + 64 * MB);
  u16* Ub = (u16*)(w + 96 * MB);
  u16* Wxb = (u16*)(w + 128 * MB);
  float* Smp = (float*)(w + 130 * MB);
  u16* Dtrb = (u16*)(w + 134 * MB);
  u16* Wdtb = (u16*)(w + 135 * MB);
  u16* Wob = (u16*)(w + 136 * MB);
  float* Schk = (float*)(w + 152 * MB);
  float* Xpart = (float*)(w + 152 * MB);  // alias: dead before Schk written
  float* Sinit = (float*)(w + 168 * MB);
  float* Dtsum = (float*)(w + 184 * MB);
  u16* Pg = (u16*)d_out;

  cvt_all<<<34304, 256, 0, stream>>>(hs, wIn, wOut, wDt, wX, Xb, Winb, Wob, Wdtb, Wxb);
  gemm256<<<dim3(32, 16), 512, 0, stream>>>(Xb, Winb, Pu, Pg, 2048);
  conv_silu<<<16384, 256, 0, stream>>>(Pu, cw, cb, Ub);
  gemm_bt<0, true><<<dim3(2, 32, 4), 256, 0, stream>>>(Ub, Wxb, Xpart, nullptr, 4096, 256);
  xp_reduce<<<1024, 256, 0, stream>>>(Xpart, Smp, Dtrb);
  gemm_bt<4><<<dim3(32, 32), 256, 0, stream>>>(Dtrb, Wdtb, Dtb, bDt, 128, 4096);
  scan_part<<<dim3(32, 16, 2), 256, 0, stream>>>(Dtb, Ub, Smp, Alog, Schk, Dtsum);
  scan_fold<<<dim3(16, 16, 2), 256, 0, stream>>>(Schk, Dtsum, Alog, Sinit);
  scan_y<<<dim3(32, 16, 2), 256, 0, stream>>>(Dtb, Ub, Smp, Pg, Alog, Dv, Sinit, Yb);
  gemm_bt<0><<<dim3(16, 32), 256, 0, stream>>>(Yb, Wob, (float*)d_out, nullptr, 4096, 2048);
}